// Round 7
// baseline (402.116 us; speedup 1.0000x reference)
//
#include <hip/hip_runtime.h>
#include <hip/hip_bf16.h>

typedef __attribute__((ext_vector_type(8))) short short8;
typedef __attribute__((ext_vector_type(4))) short short4_t;
typedef __attribute__((ext_vector_type(4))) float f32x4;
typedef unsigned short ushort_t;

#define DEV __device__ __forceinline__

DEV ushort_t f2bf(float f) {
    unsigned u = __builtin_bit_cast(unsigned, f);
    u = u + 0x7fffu + ((u >> 16) & 1u);   // RNE
    return (ushort_t)(u >> 16);
}

DEV unsigned pk_bf16(float lo, float hi) {
    __hip_bfloat162 h = __float22bfloat162_rn(make_float2(lo, hi));
    unsigned u;
    __builtin_memcpy(&u, &h, sizeof(u));   // lo in bits [15:0], hi in [31:16]
    return u;
}

DEV short8 ld8(const ushort_t* p) { return *reinterpret_cast<const short8*>(p); }

// ---------------------------------------------------------------------------
// C[M=4096, N] = A[4096,1024] @ W[1024,N] + bias, output bf16.  (r3-proven)
// Q/K rows -> outRow as [b,h,s,64]; V half (n>=1024, when outT set) -> outT
// transposed [b,h,64,s] so attention reads V kv-contiguous.
// ---------------------------------------------------------------------------
__global__ __launch_bounds__(256)
void proj_gemm(const float* __restrict__ A, const float* __restrict__ W,
               const float* __restrict__ bias, int N,
               ushort_t* __restrict__ outRow, ushort_t* __restrict__ outT)
{
    __shared__ ushort_t As[128 * 72];  // [row m 0..127][k 0..63], stride 72 (pad)
    __shared__ ushort_t Bt[128 * 72];  // [col n 0..127][k 0..63], stride 72

    const int t = threadIdx.x;
    const int lane = t & 63;
    const int wv = t >> 6;
    const int wr = wv >> 1, wc = wv & 1;
    const int c = lane & 15, g = lane >> 4;
    const int m0 = blockIdx.y * 128, n0 = blockIdx.x * 128;

    f32x4 acc[4][4];
    const f32x4 zero4 = {0.f, 0.f, 0.f, 0.f};
#pragma unroll
    for (int mi = 0; mi < 4; ++mi)
#pragma unroll
        for (int ni = 0; ni < 4; ++ni) acc[mi][ni] = zero4;

    for (int it = 0; it < 16; ++it) {
        const int k0 = it * 64;
        // stage A tile: 128 rows x 64 k (f32 -> bf16)
        {
            const int kq = (t & 15) * 4;
            int r = t >> 4;
#pragma unroll
            for (int rep = 0; rep < 8; ++rep, r += 16) {
                float4 v = *reinterpret_cast<const float4*>(
                    A + (size_t)(m0 + r) * 1024 + k0 + kq);
                ushort_t* dst = &As[r * 72 + kq];
                dst[0] = f2bf(v.x); dst[1] = f2bf(v.y);
                dst[2] = f2bf(v.z); dst[3] = f2bf(v.w);
            }
        }
        // stage W tile (64 k x 128 n), transposed into Bt[n][k]
        {
            const int nq = (t & 31) * 4;
            const int kr = t >> 5;
#pragma unroll
            for (int rep = 0; rep < 8; ++rep) {
                const int k = kr + 8 * rep;
                float4 v = *reinterpret_cast<const float4*>(
                    W + (size_t)(k0 + k) * N + n0 + nq);
                Bt[(nq + 0) * 72 + k] = f2bf(v.x);
                Bt[(nq + 1) * 72 + k] = f2bf(v.y);
                Bt[(nq + 2) * 72 + k] = f2bf(v.z);
                Bt[(nq + 3) * 72 + k] = f2bf(v.w);
            }
        }
        __syncthreads();
#pragma unroll
        for (int kk = 0; kk < 64; kk += 32) {
            short8 afr[4], bfr[4];
#pragma unroll
            for (int mi = 0; mi < 4; ++mi)
                afr[mi] = ld8(&As[(wr * 64 + mi * 16 + c) * 72 + kk + 8 * g]);
#pragma unroll
            for (int ni = 0; ni < 4; ++ni)
                bfr[ni] = ld8(&Bt[(wc * 64 + ni * 16 + c) * 72 + kk + 8 * g]);
#pragma unroll
            for (int mi = 0; mi < 4; ++mi)
#pragma unroll
                for (int ni = 0; ni < 4; ++ni)
                    acc[mi][ni] = __builtin_amdgcn_mfma_f32_16x16x32_bf16(
                        afr[mi], bfr[ni], acc[mi][ni], 0, 0, 0);
        }
        __syncthreads();
    }

    // epilogue: D row = 4*g + j (+16*mi +64*wr), col = c (+16*ni +64*wc)
#pragma unroll
    for (int mi = 0; mi < 4; ++mi) {
#pragma unroll
        for (int ni = 0; ni < 4; ++ni) {
            const int n = n0 + wc * 64 + ni * 16 + c;
            const float bb = bias[n];
#pragma unroll
            for (int j = 0; j < 4; ++j) {
                const int m = m0 + wr * 64 + mi * 16 + 4 * g + j;
                const int b = m >> 11, s = m & 2047;
                const ushort_t val = f2bf(acc[mi][ni][j] + bb);
                if (outT != nullptr && n >= 1024) {
                    const int np = n - 1024;
                    const int hh = np >> 6, d = np & 63;
                    outT[(size_t)((b * 16 + hh) * 64 + d) * 2048 + s] = val;
                } else {
                    const int hh = n >> 6, d = n & 63;
                    outRow[((size_t)((b * 16 + hh) * 2048 + s)) * 64 + d] = val;
                }
            }
        }
    }
}

// ---------------------------------------------------------------------------
// Flash attention, fixed-max softmax, PV^T. Prefetch distance 2 via 3-buffer
// rotation: body k consumes buf[k%3], prefetches tile k+2 into buf[(k+2)%3].
// ---------------------------------------------------------------------------
DEV void load_tile(const ushort_t* __restrict__ Kh, const ushort_t* __restrict__ Vh,
                   const float* __restrict__ crb, int kvb, int c, int g,
                   short8 (&K)[2][2], short8 (&V)[4], float4 (&C)[2][2])
{
#pragma unroll
    for (int ct = 0; ct < 2; ++ct)
#pragma unroll
        for (int st = 0; st < 2; ++st)
            K[ct][st] = ld8(Kh + (size_t)(kvb + ct * 16 + c) * 64 + st * 32 + 8 * g);
#pragma unroll
    for (int dt = 0; dt < 4; ++dt) {
        const ushort_t* vp = Vh + (size_t)(dt * 16 + c) * 2048 + kvb + 4 * g;
        const short4_t vlo = *reinterpret_cast<const short4_t*>(vp);
        const short4_t vhi = *reinterpret_cast<const short4_t*>(vp + 16);
        V[dt] = __builtin_shufflevector(vlo, vhi, 0, 1, 2, 3, 4, 5, 6, 7);
    }
#pragma unroll
    for (int ct = 0; ct < 2; ++ct) {
        const float* cp = crb + (size_t)(kvb + 16 * ct + 4 * g) * 2;
        C[ct][0] = *reinterpret_cast<const float4*>(cp);
        C[ct][1] = *reinterpret_cast<const float4*>(cp + 4);
    }
}

DEV void attn_body(const ushort_t* __restrict__ Kh, const ushort_t* __restrict__ Vh,
                   const float* __restrict__ crb, int nxt, int c, int g,
                   const short8 (&bq)[2][2],
                   short8 (&KC)[2][2], short8 (&VC)[4], float4 (&CC)[2][2],
                   short8 (&KN)[2][2], short8 (&VN)[4], float4 (&CN)[2][2],
                   f32x4 (&accv)[2][4], float (&lst)[2],
                   float (&a0s)[2], float (&a1s)[2])
{
    const f32x4 zero4 = {0.f, 0.f, 0.f, 0.f};
    const float SCL = 0.18033688011112042f;  // (1/8) * log2(e)

    // ---- issue tile-(k+2) loads; consumed two bodies later ----
    load_tile(Kh, Vh, crb, nxt, c, g, KN, VN, CN);

    // ---- QK^T (swapped): lane holds S^T[kv=16ct+4g+j][q=c] ----
    f32x4 sc[2][2];
#pragma unroll
    for (int qt = 0; qt < 2; ++qt)
#pragma unroll
        for (int ct = 0; ct < 2; ++ct) {
            f32x4 z = zero4;
            z = __builtin_amdgcn_mfma_f32_16x16x32_bf16(KC[ct][0], bq[qt][0], z, 0, 0, 0);
            z = __builtin_amdgcn_mfma_f32_16x16x32_bf16(KC[ct][1], bq[qt][1], z, 0, 0, 0);
            sc[qt][ct] = z;
        }

    // ---- fixed-max softmax + rank-2 cr accumulation ----
    short8 pa[2];
#pragma unroll
    for (int qt = 0; qt < 2; ++qt) {
        float e[2][4];
        float lc = lst[qt], a0c = a0s[qt], a1c = a1s[qt];
#pragma unroll
        for (int ct = 0; ct < 2; ++ct) {
            const float cr0[4] = {CC[ct][0].x, CC[ct][0].z, CC[ct][1].x, CC[ct][1].z};
            const float cr1[4] = {CC[ct][0].y, CC[ct][0].w, CC[ct][1].y, CC[ct][1].w};
#pragma unroll
            for (int j = 0; j < 4; ++j) {
                const float ev = exp2f(sc[qt][ct][j] * SCL);
                e[ct][j] = ev;
                lc  += ev;
                a0c += ev * cr0[j];
                a1c += ev * cr1[j];
            }
        }
        lst[qt] = lc; a0s[qt] = a0c; a1s[qt] = a1c;
        int4 w;
        w.x = (int)pk_bf16(e[0][0], e[0][1]);
        w.y = (int)pk_bf16(e[0][2], e[0][3]);
        w.z = (int)pk_bf16(e[1][0], e[1][1]);
        w.w = (int)pk_bf16(e[1][2], e[1][3]);
        pa[qt] = __builtin_bit_cast(short8, w);
    }

    // ---- PV^T: A=V gathered in the same kv-slot permutation as P ----
#pragma unroll
    for (int dt = 0; dt < 4; ++dt) {
        accv[0][dt] = __builtin_amdgcn_mfma_f32_16x16x32_bf16(VC[dt], pa[0], accv[0][dt], 0, 0, 0);
        accv[1][dt] = __builtin_amdgcn_mfma_f32_16x16x32_bf16(VC[dt], pa[1], accv[1][dt], 0, 0, 0);
    }
}

__global__ __launch_bounds__(256, 2)
void attn_kernel(const ushort_t* __restrict__ Qr, const ushort_t* __restrict__ Kr,
                 const ushort_t* __restrict__ Vt, const float* __restrict__ cr,
                 const float* __restrict__ Wmo, const float* __restrict__ bmo,
                 float* __restrict__ out)
{
    const int t = threadIdx.x;
    const int w = t >> 6, lane = t & 63;
    const int c = lane & 15, g = lane >> 4;

    // XCD swizzle: gid%8 ~ XCD; each XCD owns 4 whole (b,h) pairs.
    const int gid = blockIdx.x;
    const int bh = (gid & 7) + 8 * ((gid >> 3) & 3);
    const int xt = gid >> 5;
    const int b = bh >> 4, hh = bh & 15;
    const int qb = xt * 128 + w * 32;

    const ushort_t* Qh = Qr + (size_t)bh * (2048 * 64);
    const ushort_t* Kh = Kr + (size_t)bh * (2048 * 64);
    const ushort_t* Vh = Vt + (size_t)bh * (64 * 2048);
    const float*   crb = cr + (size_t)b * (2048 * 2);

    short8 bq[2][2];
#pragma unroll
    for (int qt = 0; qt < 2; ++qt)
#pragma unroll
        for (int st = 0; st < 2; ++st)
            bq[qt][st] = ld8(Qh + (size_t)(qb + qt * 16 + c) * 64 + st * 32 + 8 * g);

    f32x4 accv[2][4];
    const f32x4 zero4 = {0.f, 0.f, 0.f, 0.f};
#pragma unroll
    for (int qt = 0; qt < 2; ++qt)
#pragma unroll
        for (int dt = 0; dt < 4; ++dt) accv[qt][dt] = zero4;

    float lst[2] = {0.f, 0.f};
    float a0s[2] = {0.f, 0.f};
    float a1s[2] = {0.f, 0.f};

    short8 kaA[2][2], kaB[2][2], kaC[2][2];
    short8 vA[4], vB[4], vC[4];
    float4 cA[2][2], cB[2][2], cC[2][2];

    // prologue: tiles 0 and 32 into A and B
    load_tile(Kh, Vh, crb, 0,  c, g, kaA, vA, cA);
    load_tile(Kh, Vh, crb, 32, c, g, kaB, vB, cB);

    for (int i = 0; i < 21; ++i) {
        const int base = i * 96;
        attn_body(Kh, Vh, crb, (base + 64) & 2047, c, g, bq,
                  kaA, vA, cA, kaC, vC, cC, accv, lst, a0s, a1s);
        attn_body(Kh, Vh, crb, (base + 96) & 2047, c, g, bq,
                  kaB, vB, cB, kaA, vA, cA, accv, lst, a0s, a1s);
        attn_body(Kh, Vh, crb, (base + 128) & 2047, c, g, bq,
                  kaC, vC, cC, kaB, vB, cB, accv, lst, a0s, a1s);
    }
    // final tile 2016 (loaded into A during i=20); prefetch target unused
    attn_body(Kh, Vh, crb, 0, c, g, bq,
              kaA, vA, cA, kaC, vC, cC, accv, lst, a0s, a1s);

    // reduce stats across g (kv-subsets): every lane gets q=c totals
#pragma unroll
    for (int qt = 0; qt < 2; ++qt) {
        lst[qt] += __shfl_xor(lst[qt], 16, 64); lst[qt] += __shfl_xor(lst[qt], 32, 64);
        a0s[qt] += __shfl_xor(a0s[qt], 16, 64); a0s[qt] += __shfl_xor(a0s[qt], 32, 64);
        a1s[qt] += __shfl_xor(a1s[qt], 16, 64); a1s[qt] += __shfl_xor(a1s[qt], 32, 64);
    }

    // epilogue: accv[qt][dt] reg j -> q = qb+qt*16+c, d = dt*16+4g+j
#pragma unroll
    for (int qt = 0; qt < 2; ++qt) {
        const int q = qb + qt * 16 + c;
        const float inv = 1.f / lst[qt];
        const float a0 = a0s[qt] * inv, a1 = a1s[qt] * inv;
#pragma unroll
        for (int dt = 0; dt < 4; ++dt) {
            const int d = hh * 64 + dt * 16 + 4 * g;
            const float4 w0 = *reinterpret_cast<const float4*>(Wmo + d);
            const float4 w1 = *reinterpret_cast<const float4*>(Wmo + 1024 + d);
            const float4 bm = *reinterpret_cast<const float4*>(bmo + d);
            const size_t oidx = ((size_t)(b * 2048 + q)) * 1024 + d;
            float4 hv, mv;
            hv.x = accv[qt][dt][0] * inv; hv.y = accv[qt][dt][1] * inv;
            hv.z = accv[qt][dt][2] * inv; hv.w = accv[qt][dt][3] * inv;
            mv.x = a0 * w0.x + a1 * w1.x + bm.x;
            mv.y = a0 * w0.y + a1 * w1.y + bm.y;
            mv.z = a0 * w0.z + a1 * w1.z + bm.z;
            mv.w = a0 * w0.w + a1 * w1.w + bm.w;
            *reinterpret_cast<float4*>(out + oidx) = hv;
            *reinterpret_cast<float4*>(out + 4194304 + oidx) = mv;
        }
    }
}

// ---------------------------------------------------------------------------
extern "C" void kernel_launch(void* const* d_in, const int* in_sizes, int n_in,
                              void* d_out, int out_size, void* d_ws, size_t ws_size,
                              hipStream_t stream)
{
    const float* i1  = (const float*)d_in[0];
    const float* i2  = (const float*)d_in[1];
    const float* cr  = (const float*)d_in[2];
    const float* Wq  = (const float*)d_in[3];
    const float* bq  = (const float*)d_in[4];
    const float* Wkv = (const float*)d_in[5];
    const float* bkv = (const float*)d_in[6];
    const float* Wmo = (const float*)d_in[7];
    const float* bmo = (const float*)d_in[8];
    float* out = (float*)d_out;

    ushort_t* Qr = (ushort_t*)d_ws;          // [2,16,2048,64] bf16 (8 MB)
    ushort_t* Kr = Qr + 4194304;             // [2,16,2048,64] bf16 (8 MB)
    ushort_t* Vt = Kr + 4194304;             // [2,16,64,2048] bf16 (8 MB)

    proj_gemm<<<dim3(8, 32), dim3(256), 0, stream>>>(i1, Wq, bq, 1024, Qr, nullptr);
    proj_gemm<<<dim3(16, 32), dim3(256), 0, stream>>>(i2, Wkv, bkv, 2048, Kr, Vt);
    attn_kernel<<<dim3(512), dim3(256), 0, stream>>>(Qr, Kr, Vt, cr, Wmo, bmo, out);
}

// Round 8
// 254.925 us; speedup vs baseline: 1.5774x; 1.5774x over previous
//
#include <hip/hip_runtime.h>
#include <hip/hip_bf16.h>

typedef __attribute__((ext_vector_type(8))) short short8;
typedef __attribute__((ext_vector_type(4))) short short4_t;
typedef __attribute__((ext_vector_type(4))) float f32x4;
typedef unsigned short ushort_t;

#define DEV __device__ __forceinline__

DEV ushort_t f2bf(float f) {
    unsigned u = __builtin_bit_cast(unsigned, f);
    u = u + 0x7fffu + ((u >> 16) & 1u);   // RNE
    return (ushort_t)(u >> 16);
}

DEV unsigned pk_bf16(float lo, float hi) {
    __hip_bfloat162 h = __float22bfloat162_rn(make_float2(lo, hi));
    unsigned u;
    __builtin_memcpy(&u, &h, sizeof(u));   // lo in bits [15:0], hi in [31:16]
    return u;
}

DEV short8 ld8(const ushort_t* p) { return *reinterpret_cast<const short8*>(p); }

// ---------------------------------------------------------------------------
// C[M=4096, N] = A[4096,1024] @ W[1024,N] + bias, output bf16.  (r3-proven)
// ---------------------------------------------------------------------------
__global__ __launch_bounds__(256)
void proj_gemm(const float* __restrict__ A, const float* __restrict__ W,
               const float* __restrict__ bias, int N,
               ushort_t* __restrict__ outRow, ushort_t* __restrict__ outT)
{
    __shared__ ushort_t As[128 * 72];
    __shared__ ushort_t Bt[128 * 72];

    const int t = threadIdx.x;
    const int lane = t & 63;
    const int wv = t >> 6;
    const int wr = wv >> 1, wc = wv & 1;
    const int c = lane & 15, g = lane >> 4;
    const int m0 = blockIdx.y * 128, n0 = blockIdx.x * 128;

    f32x4 acc[4][4];
    const f32x4 zero4 = {0.f, 0.f, 0.f, 0.f};
#pragma unroll
    for (int mi = 0; mi < 4; ++mi)
#pragma unroll
        for (int ni = 0; ni < 4; ++ni) acc[mi][ni] = zero4;

    for (int it = 0; it < 16; ++it) {
        const int k0 = it * 64;
        {
            const int kq = (t & 15) * 4;
            int r = t >> 4;
#pragma unroll
            for (int rep = 0; rep < 8; ++rep, r += 16) {
                float4 v = *reinterpret_cast<const float4*>(
                    A + (size_t)(m0 + r) * 1024 + k0 + kq);
                ushort_t* dst = &As[r * 72 + kq];
                dst[0] = f2bf(v.x); dst[1] = f2bf(v.y);
                dst[2] = f2bf(v.z); dst[3] = f2bf(v.w);
            }
        }
        {
            const int nq = (t & 31) * 4;
            const int kr = t >> 5;
#pragma unroll
            for (int rep = 0; rep < 8; ++rep) {
                const int k = kr + 8 * rep;
                float4 v = *reinterpret_cast<const float4*>(
                    W + (size_t)(k0 + k) * N + n0 + nq);
                Bt[(nq + 0) * 72 + k] = f2bf(v.x);
                Bt[(nq + 1) * 72 + k] = f2bf(v.y);
                Bt[(nq + 2) * 72 + k] = f2bf(v.z);
                Bt[(nq + 3) * 72 + k] = f2bf(v.w);
            }
        }
        __syncthreads();
#pragma unroll
        for (int kk = 0; kk < 64; kk += 32) {
            short8 afr[4], bfr[4];
#pragma unroll
            for (int mi = 0; mi < 4; ++mi)
                afr[mi] = ld8(&As[(wr * 64 + mi * 16 + c) * 72 + kk + 8 * g]);
#pragma unroll
            for (int ni = 0; ni < 4; ++ni)
                bfr[ni] = ld8(&Bt[(wc * 64 + ni * 16 + c) * 72 + kk + 8 * g]);
#pragma unroll
            for (int mi = 0; mi < 4; ++mi)
#pragma unroll
                for (int ni = 0; ni < 4; ++ni)
                    acc[mi][ni] = __builtin_amdgcn_mfma_f32_16x16x32_bf16(
                        afr[mi], bfr[ni], acc[mi][ni], 0, 0, 0);
        }
        __syncthreads();
    }

#pragma unroll
    for (int mi = 0; mi < 4; ++mi) {
#pragma unroll
        for (int ni = 0; ni < 4; ++ni) {
            const int n = n0 + wc * 64 + ni * 16 + c;
            const float bb = bias[n];
#pragma unroll
            for (int j = 0; j < 4; ++j) {
                const int m = m0 + wr * 64 + mi * 16 + 4 * g + j;
                const int b = m >> 11, s = m & 2047;
                const ushort_t val = f2bf(acc[mi][ni][j] + bb);
                if (outT != nullptr && n >= 1024) {
                    const int np = n - 1024;
                    const int hh = np >> 6, d = np & 63;
                    outT[(size_t)((b * 16 + hh) * 64 + d) * 2048 + s] = val;
                } else {
                    const int hh = n >> 6, d = n & 63;
                    outRow[((size_t)((b * 16 + hh) * 2048 + s)) * 64 + d] = val;
                }
            }
        }
    }
}

// ---------------------------------------------------------------------------
// Flash attention, fixed-max softmax, PV^T. Block-level LDS double-buffered
// staging (T14 async-split): per body, each thread issues 2 global 16B loads
// (next K/V tile), computes current tile from LDS, then ds_writes the staged
// regs into the other buffer and barriers once. Padded LDS strides 72/40
// (rows 144 B / 80 B, 16B-aligned, <=2-way bank conflicts).
// ---------------------------------------------------------------------------
DEV void attn_body(const ushort_t* __restrict__ Kh, const ushort_t* __restrict__ Vh,
                   const float* __restrict__ crb, int kv_next,
                   const ushort_t* KsC, const ushort_t* VsC,
                   ushort_t* KsN, ushort_t* VsN,
                   int c, int g, int rk, int ck, int rv, int cv,
                   const short8 (&bq)[2][2],
                   float4 (&CC)[2][2], float4 (&CN)[2][2],
                   f32x4 (&accv)[2][4], float (&lst)[2],
                   float (&a0s)[2], float (&a1s)[2])
{
    const f32x4 zero4 = {0.f, 0.f, 0.f, 0.f};
    const float SCL = 0.18033688011112042f;  // (1/8) * log2(e)

    // ---- issue next-tile staging loads; pinned above compute ----
    const short8 kreg = ld8(Kh + (size_t)(kv_next + rk) * 64 + ck);
    const short8 vreg = ld8(Vh + (size_t)rv * 2048 + kv_next + cv);
    {
        const float* cp0 = crb + (size_t)(kv_next + 4 * g) * 2;
        CN[0][0] = *reinterpret_cast<const float4*>(cp0);
        CN[0][1] = *reinterpret_cast<const float4*>(cp0 + 4);
        const float* cp1 = crb + (size_t)(kv_next + 16 + 4 * g) * 2;
        CN[1][0] = *reinterpret_cast<const float4*>(cp1);
        CN[1][1] = *reinterpret_cast<const float4*>(cp1 + 4);
    }
    __builtin_amdgcn_sched_barrier(0);

    // ---- LDS -> fragments ----
    short8 KC[2][2];
#pragma unroll
    for (int ct = 0; ct < 2; ++ct)
#pragma unroll
        for (int st = 0; st < 2; ++st)
            KC[ct][st] = ld8(&KsC[(ct * 16 + c) * 72 + st * 32 + 8 * g]);
    short8 VC[4];
#pragma unroll
    for (int dt = 0; dt < 4; ++dt) {
        const short4_t vlo = *reinterpret_cast<const short4_t*>(&VsC[(dt * 16 + c) * 40 + 4 * g]);
        const short4_t vhi = *reinterpret_cast<const short4_t*>(&VsC[(dt * 16 + c) * 40 + 4 * g + 16]);
        VC[dt] = __builtin_shufflevector(vlo, vhi, 0, 1, 2, 3, 4, 5, 6, 7);
    }

    // ---- QK^T (swapped): lane holds S^T[kv=16ct+4g+j][q=c] ----
    f32x4 sc[2][2];
#pragma unroll
    for (int qt = 0; qt < 2; ++qt)
#pragma unroll
        for (int ct = 0; ct < 2; ++ct) {
            f32x4 z = zero4;
            z = __builtin_amdgcn_mfma_f32_16x16x32_bf16(KC[ct][0], bq[qt][0], z, 0, 0, 0);
            z = __builtin_amdgcn_mfma_f32_16x16x32_bf16(KC[ct][1], bq[qt][1], z, 0, 0, 0);
            sc[qt][ct] = z;
        }

    // ---- fixed-max softmax + rank-2 cr accumulation ----
    short8 pa[2];
#pragma unroll
    for (int qt = 0; qt < 2; ++qt) {
        float e[2][4];
        float lc = lst[qt], a0c = a0s[qt], a1c = a1s[qt];
#pragma unroll
        for (int ct = 0; ct < 2; ++ct) {
            const float cr0[4] = {CC[ct][0].x, CC[ct][0].z, CC[ct][1].x, CC[ct][1].z};
            const float cr1[4] = {CC[ct][0].y, CC[ct][0].w, CC[ct][1].y, CC[ct][1].w};
#pragma unroll
            for (int j = 0; j < 4; ++j) {
                const float ev = exp2f(sc[qt][ct][j] * SCL);
                e[ct][j] = ev;
                lc  += ev;
                a0c += ev * cr0[j];
                a1c += ev * cr1[j];
            }
        }
        lst[qt] = lc; a0s[qt] = a0c; a1s[qt] = a1c;
        int4 w;
        w.x = (int)pk_bf16(e[0][0], e[0][1]);
        w.y = (int)pk_bf16(e[0][2], e[0][3]);
        w.z = (int)pk_bf16(e[1][0], e[1][1]);
        w.w = (int)pk_bf16(e[1][2], e[1][3]);
        pa[qt] = __builtin_bit_cast(short8, w);
    }

    // ---- PV^T: A=V gathered in the same kv-slot permutation as P ----
#pragma unroll
    for (int dt = 0; dt < 4; ++dt) {
        accv[0][dt] = __builtin_amdgcn_mfma_f32_16x16x32_bf16(VC[dt], pa[0], accv[0][dt], 0, 0, 0);
        accv[1][dt] = __builtin_amdgcn_mfma_f32_16x16x32_bf16(VC[dt], pa[1], accv[1][dt], 0, 0, 0);
    }

    // ---- write staged tile into next buffer; one barrier per body ----
    *reinterpret_cast<short8*>(&KsN[rk * 72 + ck]) = kreg;
    *reinterpret_cast<short8*>(&VsN[rv * 40 + cv]) = vreg;
    __syncthreads();
}

__global__ __launch_bounds__(256, 2)
void attn_kernel(const ushort_t* __restrict__ Qr, const ushort_t* __restrict__ Kr,
                 const ushort_t* __restrict__ Vt, const float* __restrict__ cr,
                 const float* __restrict__ Wmo, const float* __restrict__ bmo,
                 float* __restrict__ out)
{
    __shared__ ushort_t Ks[2][32 * 72];
    __shared__ ushort_t Vs[2][64 * 40];

    const int t = threadIdx.x;
    const int w = t >> 6, lane = t & 63;
    const int c = lane & 15, g = lane >> 4;
    const int rk = t >> 3, ck = (t & 7) * 8;   // K staging: 32 rows x 64 cols
    const int rv = t >> 2, cv = (t & 3) * 8;   // V staging: 64 rows x 32 cols

    // XCD swizzle: gid%8 ~ XCD; each XCD owns 4 whole (b,h) pairs.
    const int gid = blockIdx.x;
    const int bh = (gid & 7) + 8 * ((gid >> 3) & 3);
    const int xt = gid >> 5;
    const int b = bh >> 4, hh = bh & 15;
    const int qb = xt * 128 + w * 32;

    const ushort_t* Qh = Qr + (size_t)bh * (2048 * 64);
    const ushort_t* Kh = Kr + (size_t)bh * (2048 * 64);
    const ushort_t* Vh = Vt + (size_t)bh * (64 * 2048);
    const float*   crb = cr + (size_t)b * (2048 * 2);

    short8 bq[2][2];
#pragma unroll
    for (int qt = 0; qt < 2; ++qt)
#pragma unroll
        for (int st = 0; st < 2; ++st)
            bq[qt][st] = ld8(Qh + (size_t)(qb + qt * 16 + c) * 64 + st * 32 + 8 * g);

    f32x4 accv[2][4];
    const f32x4 zero4 = {0.f, 0.f, 0.f, 0.f};
#pragma unroll
    for (int qt = 0; qt < 2; ++qt)
#pragma unroll
        for (int dt = 0; dt < 4; ++dt) accv[qt][dt] = zero4;

    float lst[2] = {0.f, 0.f};
    float a0s[2] = {0.f, 0.f};
    float a1s[2] = {0.f, 0.f};

    float4 cA[2][2], cB[2][2];

    // prologue: stage tile 0 into buf0, cr tile 0 into cA
    {
        const short8 k0 = ld8(Kh + (size_t)rk * 64 + ck);
        const short8 v0 = ld8(Vh + (size_t)rv * 2048 + cv);
        *reinterpret_cast<short8*>(&Ks[0][rk * 72 + ck]) = k0;
        *reinterpret_cast<short8*>(&Vs[0][rv * 40 + cv]) = v0;
        const float* cp0 = crb + (size_t)(4 * g) * 2;
        cA[0][0] = *reinterpret_cast<const float4*>(cp0);
        cA[0][1] = *reinterpret_cast<const float4*>(cp0 + 4);
        const float* cp1 = crb + (size_t)(16 + 4 * g) * 2;
        cA[1][0] = *reinterpret_cast<const float4*>(cp1);
        cA[1][1] = *reinterpret_cast<const float4*>(cp1 + 4);
    }
    __syncthreads();

    for (int i = 0; i < 32; ++i) {
        const int kvb = i * 64;
        attn_body(Kh, Vh, crb, kvb + 32,
                  &Ks[0][0], &Vs[0][0], &Ks[1][0], &Vs[1][0],
                  c, g, rk, ck, rv, cv, bq, cA, cB,
                  accv, lst, a0s, a1s);
        attn_body(Kh, Vh, crb, (kvb + 64) & 2047,
                  &Ks[1][0], &Vs[1][0], &Ks[0][0], &Vs[0][0],
                  c, g, rk, ck, rv, cv, bq, cB, cA,
                  accv, lst, a0s, a1s);
    }

    // reduce stats across g (kv-subsets): every lane gets q=c totals
#pragma unroll
    for (int qt = 0; qt < 2; ++qt) {
        lst[qt] += __shfl_xor(lst[qt], 16, 64); lst[qt] += __shfl_xor(lst[qt], 32, 64);
        a0s[qt] += __shfl_xor(a0s[qt], 16, 64); a0s[qt] += __shfl_xor(a0s[qt], 32, 64);
        a1s[qt] += __shfl_xor(a1s[qt], 16, 64); a1s[qt] += __shfl_xor(a1s[qt], 32, 64);
    }

    // epilogue: accv[qt][dt] reg j -> q = qb+qt*16+c, d = dt*16+4g+j
#pragma unroll
    for (int qt = 0; qt < 2; ++qt) {
        const int q = qb + qt * 16 + c;
        const float inv = 1.f / lst[qt];
        const float a0 = a0s[qt] * inv, a1 = a1s[qt] * inv;
#pragma unroll
        for (int dt = 0; dt < 4; ++dt) {
            const int d = hh * 64 + dt * 16 + 4 * g;
            const float4 w0 = *reinterpret_cast<const float4*>(Wmo + d);
            const float4 w1 = *reinterpret_cast<const float4*>(Wmo + 1024 + d);
            const float4 bm = *reinterpret_cast<const float4*>(bmo + d);
            const size_t oidx = ((size_t)(b * 2048 + q)) * 1024 + d;
            float4 hv, mv;
            hv.x = accv[qt][dt][0] * inv; hv.y = accv[qt][dt][1] * inv;
            hv.z = accv[qt][dt][2] * inv; hv.w = accv[qt][dt][3] * inv;
            mv.x = a0 * w0.x + a1 * w1.x + bm.x;
            mv.y = a0 * w0.y + a1 * w1.y + bm.y;
            mv.z = a0 * w0.z + a1 * w1.z + bm.z;
            mv.w = a0 * w0.w + a1 * w1.w + bm.w;
            *reinterpret_cast<float4*>(out + oidx) = hv;
            *reinterpret_cast<float4*>(out + 4194304 + oidx) = mv;
        }
    }
}

// ---------------------------------------------------------------------------
extern "C" void kernel_launch(void* const* d_in, const int* in_sizes, int n_in,
                              void* d_out, int out_size, void* d_ws, size_t ws_size,
                              hipStream_t stream)
{
    const float* i1  = (const float*)d_in[0];
    const float* i2  = (const float*)d_in[1];
    const float* cr  = (const float*)d_in[2];
    const float* Wq  = (const float*)d_in[3];
    const float* bq  = (const float*)d_in[4];
    const float* Wkv = (const float*)d_in[5];
    const float* bkv = (const float*)d_in[6];
    const float* Wmo = (const float*)d_in[7];
    const float* bmo = (const float*)d_in[8];
    float* out = (float*)d_out;

    ushort_t* Qr = (ushort_t*)d_ws;          // [2,16,2048,64] bf16 (8 MB)
    ushort_t* Kr = Qr + 4194304;             // [2,16,2048,64] bf16 (8 MB)
    ushort_t* Vt = Kr + 4194304;             // [2,16,64,2048] bf16 (8 MB)

    proj_gemm<<<dim3(8, 32), dim3(256), 0, stream>>>(i1, Wq, bq, 1024, Qr, nullptr);
    proj_gemm<<<dim3(16, 32), dim3(256), 0, stream>>>(i2, Wkv, bkv, 2048, Kr, Vt);
    attn_kernel<<<dim3(512), dim3(256), 0, stream>>>(Qr, Kr, Vt, cr, Wmo, bmo, out);
}

// Round 9
// 147.882 us; speedup vs baseline: 2.7192x; 1.7238x over previous
//
#include <hip/hip_runtime.h>
#include <hip/hip_bf16.h>

typedef __attribute__((ext_vector_type(8))) short short8;
typedef __attribute__((ext_vector_type(4))) short short4_t;
typedef __attribute__((ext_vector_type(4))) float f32x4;
typedef unsigned short ushort_t;

#define DEV __device__ __forceinline__

DEV ushort_t f2bf(float f) {
    unsigned u = __builtin_bit_cast(unsigned, f);
    u = u + 0x7fffu + ((u >> 16) & 1u);   // RNE
    return (ushort_t)(u >> 16);
}

DEV unsigned pk_bf16(float lo, float hi) {
    __hip_bfloat162 h = __float22bfloat162_rn(make_float2(lo, hi));
    unsigned u;
    __builtin_memcpy(&u, &h, sizeof(u));
    return u;
}

DEV short8 ld8(const ushort_t* p) { return *reinterpret_cast<const short8*>(p); }

// ---------------------------------------------------------------------------
// prep: f32 -> bf16 elementwise (grid*256*8 == n exactly)
// ---------------------------------------------------------------------------
__global__ __launch_bounds__(256)
void cvt_bf16(const float* __restrict__ in, ushort_t* __restrict__ out)
{
    const size_t i = ((size_t)blockIdx.x * 256 + threadIdx.x) * 8;
    const float4 a = *reinterpret_cast<const float4*>(in + i);
    const float4 b = *reinterpret_cast<const float4*>(in + i + 4);
    short8 v;
    v[0] = (short)f2bf(a.x); v[1] = (short)f2bf(a.y);
    v[2] = (short)f2bf(a.z); v[3] = (short)f2bf(a.w);
    v[4] = (short)f2bf(b.x); v[5] = (short)f2bf(b.y);
    v[6] = (short)f2bf(b.z); v[7] = (short)f2bf(b.w);
    *reinterpret_cast<short8*>(out + i) = v;
}

// ---------------------------------------------------------------------------
// prep: W[K][N] f32 -> Wt[N][K] bf16 (64x64 tiles via LDS)
// ---------------------------------------------------------------------------
__global__ __launch_bounds__(256)
void tcvt_bf16(const float* __restrict__ W, ushort_t* __restrict__ Wt, int K, int N)
{
    __shared__ ushort_t tile[64][72];
    const int t = threadIdx.x;
    const int nx = blockIdx.x * 64, ky = blockIdx.y * 64;
    const int r = t >> 2, q = (t & 3) * 16;

    const float* src = W + (size_t)(ky + r) * N + nx + q;
#pragma unroll
    for (int i = 0; i < 4; ++i) {
        const float4 v = *reinterpret_cast<const float4*>(src + 4 * i);
        tile[r][q + 4 * i + 0] = f2bf(v.x);
        tile[r][q + 4 * i + 1] = f2bf(v.y);
        tile[r][q + 4 * i + 2] = f2bf(v.z);
        tile[r][q + 4 * i + 3] = f2bf(v.w);
    }
    __syncthreads();
    short8 o0, o1;
#pragma unroll
    for (int i = 0; i < 8; ++i) {
        o0[i] = (short)tile[q + i][r];
        o1[i] = (short)tile[q + 8 + i][r];
    }
    ushort_t* dst = Wt + (size_t)(nx + r) * K + ky + q;
    *reinterpret_cast<short8*>(dst) = o0;
    *reinterpret_cast<short8*>(dst + 8) = o1;
}

// ---------------------------------------------------------------------------
// Fused projections (fast path): nblk<8 -> Q = A1 @ WqT; else KV = A2 @ WkvT.
// A [4096][1024] bf16, Wt [N][1024] bf16. 128x128 tile, BK=64. Staging is
// pure ld8->st8 (complete coverage: row=ch>>3, kq=(ch&7)*8 -- r4's bug fixed).
// ---------------------------------------------------------------------------
__global__ __launch_bounds__(256, 2)
void proj_all(const ushort_t* __restrict__ A1, const ushort_t* __restrict__ A2,
              const ushort_t* __restrict__ Wqt, const ushort_t* __restrict__ Wkvt,
              const float* __restrict__ bqv, const float* __restrict__ bkv,
              ushort_t* __restrict__ Qr, ushort_t* __restrict__ Kr,
              ushort_t* __restrict__ Vt)
{
    __shared__ ushort_t As[128 * 72];
    __shared__ ushort_t Bs[128 * 72];

    const int t = threadIdx.x;
    const int lane = t & 63;
    const int wv = t >> 6;
    const int wr = wv >> 1, wc = wv & 1;
    const int c = lane & 15, g = lane >> 4;
    const int m0 = blockIdx.y * 128;
    const int nblk = blockIdx.x;

    const ushort_t* A;
    const ushort_t* Wt;
    const float* bias;
    int n0;
    if (nblk < 8) { A = A1; Wt = Wqt;  bias = bqv; n0 = nblk * 128; }
    else          { A = A2; Wt = Wkvt; bias = bkv; n0 = (nblk - 8) * 128; }
    const bool isQ = (nblk < 8);

    f32x4 acc[4][4];
    const f32x4 zero4 = {0.f, 0.f, 0.f, 0.f};
#pragma unroll
    for (int mi = 0; mi < 4; ++mi)
#pragma unroll
        for (int ni = 0; ni < 4; ++ni) acc[mi][ni] = zero4;

    // staging chunk map: ch = t + 256*rep, rep 0..3 -> full 128x64 tile
    const int srow[4] = { (t + 0)   >> 3, (t + 256) >> 3, (t + 512) >> 3, (t + 768) >> 3 };
    const int skq     = (t & 7) * 8;

    short8 a_reg[4], b_reg[4];
#pragma unroll
    for (int rep = 0; rep < 4; ++rep) {
        a_reg[rep] = ld8(A  + (size_t)(m0 + srow[rep]) * 1024 + skq);
        b_reg[rep] = ld8(Wt + (size_t)(n0 + srow[rep]) * 1024 + skq);
    }

    for (int it = 0; it < 16; ++it) {
        // write staged tile
#pragma unroll
        for (int rep = 0; rep < 4; ++rep) {
            *reinterpret_cast<short8*>(&As[srow[rep] * 72 + skq]) = a_reg[rep];
            *reinterpret_cast<short8*>(&Bs[srow[rep] * 72 + skq]) = b_reg[rep];
        }
        __syncthreads();
        // issue next-tile loads (hidden under compute below)
        if (it < 15) {
            const int k1 = (it + 1) * 64;
#pragma unroll
            for (int rep = 0; rep < 4; ++rep) {
                a_reg[rep] = ld8(A  + (size_t)(m0 + srow[rep]) * 1024 + k1 + skq);
                b_reg[rep] = ld8(Wt + (size_t)(n0 + srow[rep]) * 1024 + k1 + skq);
            }
        }
        // compute from LDS
#pragma unroll
        for (int kk = 0; kk < 64; kk += 32) {
            short8 afr[4], bfr[4];
#pragma unroll
            for (int mi = 0; mi < 4; ++mi)
                afr[mi] = ld8(&As[(wr * 64 + mi * 16 + c) * 72 + kk + 8 * g]);
#pragma unroll
            for (int ni = 0; ni < 4; ++ni)
                bfr[ni] = ld8(&Bs[(wc * 64 + ni * 16 + c) * 72 + kk + 8 * g]);
#pragma unroll
            for (int mi = 0; mi < 4; ++mi)
#pragma unroll
                for (int ni = 0; ni < 4; ++ni)
                    acc[mi][ni] = __builtin_amdgcn_mfma_f32_16x16x32_bf16(
                        afr[mi], bfr[ni], acc[mi][ni], 0, 0, 0);
        }
        __syncthreads();
    }

    // epilogue: D row = 4*g+j (+16mi+64wr), col = c (+16ni+64wc)
#pragma unroll
    for (int mi = 0; mi < 4; ++mi) {
#pragma unroll
        for (int ni = 0; ni < 4; ++ni) {
            const int n = n0 + wc * 64 + ni * 16 + c;
            const float bb = bias[n];
#pragma unroll
            for (int j = 0; j < 4; ++j) {
                const int m = m0 + wr * 64 + mi * 16 + 4 * g + j;
                const int b = m >> 11, s = m & 2047;
                const ushort_t val = f2bf(acc[mi][ni][j] + bb);
                if (isQ) {
                    Qr[((size_t)((b * 16 + (n >> 6)) * 2048 + s)) * 64 + (n & 63)] = val;
                } else if (n < 1024) {
                    Kr[((size_t)((b * 16 + (n >> 6)) * 2048 + s)) * 64 + (n & 63)] = val;
                } else {
                    const int np = n - 1024;
                    Vt[(size_t)((b * 16 + (np >> 6)) * 64 + (np & 63)) * 2048 + s] = val;
                }
            }
        }
    }
}

// ---------------------------------------------------------------------------
// Fallback projection (r3/r8-proven): used if ws_size is too small for prep.
// ---------------------------------------------------------------------------
__global__ __launch_bounds__(256)
void proj_gemm(const float* __restrict__ A, const float* __restrict__ W,
               const float* __restrict__ bias, int N,
               ushort_t* __restrict__ outRow, ushort_t* __restrict__ outT)
{
    __shared__ ushort_t As[128 * 72];
    __shared__ ushort_t Bt[128 * 72];

    const int t = threadIdx.x;
    const int lane = t & 63;
    const int wv = t >> 6;
    const int wr = wv >> 1, wc = wv & 1;
    const int c = lane & 15, g = lane >> 4;
    const int m0 = blockIdx.y * 128, n0 = blockIdx.x * 128;

    f32x4 acc[4][4];
    const f32x4 zero4 = {0.f, 0.f, 0.f, 0.f};
#pragma unroll
    for (int mi = 0; mi < 4; ++mi)
#pragma unroll
        for (int ni = 0; ni < 4; ++ni) acc[mi][ni] = zero4;

    for (int it = 0; it < 16; ++it) {
        const int k0 = it * 64;
        {
            const int kq = (t & 15) * 4;
            int r = t >> 4;
#pragma unroll
            for (int rep = 0; rep < 8; ++rep, r += 16) {
                float4 v = *reinterpret_cast<const float4*>(
                    A + (size_t)(m0 + r) * 1024 + k0 + kq);
                ushort_t* dst = &As[r * 72 + kq];
                dst[0] = f2bf(v.x); dst[1] = f2bf(v.y);
                dst[2] = f2bf(v.z); dst[3] = f2bf(v.w);
            }
        }
        {
            const int nq = (t & 31) * 4;
            const int kr = t >> 5;
#pragma unroll
            for (int rep = 0; rep < 8; ++rep) {
                const int k = kr + 8 * rep;
                float4 v = *reinterpret_cast<const float4*>(
                    W + (size_t)(k0 + k) * N + n0 + nq);
                Bt[(nq + 0) * 72 + k] = f2bf(v.x);
                Bt[(nq + 1) * 72 + k] = f2bf(v.y);
                Bt[(nq + 2) * 72 + k] = f2bf(v.z);
                Bt[(nq + 3) * 72 + k] = f2bf(v.w);
            }
        }
        __syncthreads();
#pragma unroll
        for (int kk = 0; kk < 64; kk += 32) {
            short8 afr[4], bfr[4];
#pragma unroll
            for (int mi = 0; mi < 4; ++mi)
                afr[mi] = ld8(&As[(wr * 64 + mi * 16 + c) * 72 + kk + 8 * g]);
#pragma unroll
            for (int ni = 0; ni < 4; ++ni)
                bfr[ni] = ld8(&Bt[(wc * 64 + ni * 16 + c) * 72 + kk + 8 * g]);
#pragma unroll
            for (int mi = 0; mi < 4; ++mi)
#pragma unroll
                for (int ni = 0; ni < 4; ++ni)
                    acc[mi][ni] = __builtin_amdgcn_mfma_f32_16x16x32_bf16(
                        afr[mi], bfr[ni], acc[mi][ni], 0, 0, 0);
        }
        __syncthreads();
    }

#pragma unroll
    for (int mi = 0; mi < 4; ++mi) {
#pragma unroll
        for (int ni = 0; ni < 4; ++ni) {
            const int n = n0 + wc * 64 + ni * 16 + c;
            const float bb = bias[n];
#pragma unroll
            for (int j = 0; j < 4; ++j) {
                const int m = m0 + wr * 64 + mi * 16 + 4 * g + j;
                const int b = m >> 11, s = m & 2047;
                const ushort_t val = f2bf(acc[mi][ni][j] + bb);
                if (outT != nullptr && n >= 1024) {
                    const int np = n - 1024;
                    const int hh = np >> 6, d = np & 63;
                    outT[(size_t)((b * 16 + hh) * 64 + d) * 2048 + s] = val;
                } else {
                    const int hh = n >> 6, d = n & 63;
                    outRow[((size_t)((b * 16 + hh) * 2048 + s)) * 64 + d] = val;
                }
            }
        }
    }
}

// ---------------------------------------------------------------------------
// Flash attention (r8-proven): fixed-max softmax, PV^T, LDS double-buffered.
// ---------------------------------------------------------------------------
DEV void attn_body(const ushort_t* __restrict__ Kh, const ushort_t* __restrict__ Vh,
                   const float* __restrict__ crb, int kv_next,
                   const ushort_t* KsC, const ushort_t* VsC,
                   ushort_t* KsN, ushort_t* VsN,
                   int c, int g, int rk, int ck, int rv, int cv,
                   const short8 (&bq)[2][2],
                   float4 (&CC)[2][2], float4 (&CN)[2][2],
                   f32x4 (&accv)[2][4], float (&lst)[2],
                   float (&a0s)[2], float (&a1s)[2])
{
    const f32x4 zero4 = {0.f, 0.f, 0.f, 0.f};
    const float SCL = 0.18033688011112042f;  // (1/8) * log2(e)

    const short8 kreg = ld8(Kh + (size_t)(kv_next + rk) * 64 + ck);
    const short8 vreg = ld8(Vh + (size_t)rv * 2048 + kv_next + cv);
    {
        const float* cp0 = crb + (size_t)(kv_next + 4 * g) * 2;
        CN[0][0] = *reinterpret_cast<const float4*>(cp0);
        CN[0][1] = *reinterpret_cast<const float4*>(cp0 + 4);
        const float* cp1 = crb + (size_t)(kv_next + 16 + 4 * g) * 2;
        CN[1][0] = *reinterpret_cast<const float4*>(cp1);
        CN[1][1] = *reinterpret_cast<const float4*>(cp1 + 4);
    }
    __builtin_amdgcn_sched_barrier(0);

    short8 KC[2][2];
#pragma unroll
    for (int ct = 0; ct < 2; ++ct)
#pragma unroll
        for (int st = 0; st < 2; ++st)
            KC[ct][st] = ld8(&KsC[(ct * 16 + c) * 72 + st * 32 + 8 * g]);
    short8 VC[4];
#pragma unroll
    for (int dt = 0; dt < 4; ++dt) {
        const short4_t vlo = *reinterpret_cast<const short4_t*>(&VsC[(dt * 16 + c) * 40 + 4 * g]);
        const short4_t vhi = *reinterpret_cast<const short4_t*>(&VsC[(dt * 16 + c) * 40 + 4 * g + 16]);
        VC[dt] = __builtin_shufflevector(vlo, vhi, 0, 1, 2, 3, 4, 5, 6, 7);
    }

    f32x4 sc[2][2];
#pragma unroll
    for (int qt = 0; qt < 2; ++qt)
#pragma unroll
        for (int ct = 0; ct < 2; ++ct) {
            f32x4 z = zero4;
            z = __builtin_amdgcn_mfma_f32_16x16x32_bf16(KC[ct][0], bq[qt][0], z, 0, 0, 0);
            z = __builtin_amdgcn_mfma_f32_16x16x32_bf16(KC[ct][1], bq[qt][1], z, 0, 0, 0);
            sc[qt][ct] = z;
        }

    short8 pa[2];
#pragma unroll
    for (int qt = 0; qt < 2; ++qt) {
        float e[2][4];
        float lc = lst[qt], a0c = a0s[qt], a1c = a1s[qt];
#pragma unroll
        for (int ct = 0; ct < 2; ++ct) {
            const float cr0[4] = {CC[ct][0].x, CC[ct][0].z, CC[ct][1].x, CC[ct][1].z};
            const float cr1[4] = {CC[ct][0].y, CC[ct][0].w, CC[ct][1].y, CC[ct][1].w};
#pragma unroll
            for (int j = 0; j < 4; ++j) {
                const float ev = exp2f(sc[qt][ct][j] * SCL);
                e[ct][j] = ev;
                lc  += ev;
                a0c += ev * cr0[j];
                a1c += ev * cr1[j];
            }
        }
        lst[qt] = lc; a0s[qt] = a0c; a1s[qt] = a1c;
        int4 w;
        w.x = (int)pk_bf16(e[0][0], e[0][1]);
        w.y = (int)pk_bf16(e[0][2], e[0][3]);
        w.z = (int)pk_bf16(e[1][0], e[1][1]);
        w.w = (int)pk_bf16(e[1][2], e[1][3]);
        pa[qt] = __builtin_bit_cast(short8, w);
    }

#pragma unroll
    for (int dt = 0; dt < 4; ++dt) {
        accv[0][dt] = __builtin_amdgcn_mfma_f32_16x16x32_bf16(VC[dt], pa[0], accv[0][dt], 0, 0, 0);
        accv[1][dt] = __builtin_amdgcn_mfma_f32_16x16x32_bf16(VC[dt], pa[1], accv[1][dt], 0, 0, 0);
    }

    *reinterpret_cast<short8*>(&KsN[rk * 72 + ck]) = kreg;
    *reinterpret_cast<short8*>(&VsN[rv * 40 + cv]) = vreg;
    __syncthreads();
}

__global__ __launch_bounds__(256, 2)
void attn_kernel(const ushort_t* __restrict__ Qr, const ushort_t* __restrict__ Kr,
                 const ushort_t* __restrict__ Vt, const float* __restrict__ cr,
                 const float* __restrict__ Wmo, const float* __restrict__ bmo,
                 float* __restrict__ out)
{
    __shared__ ushort_t Ks[2][32 * 72];
    __shared__ ushort_t Vs[2][64 * 40];

    const int t = threadIdx.x;
    const int w = t >> 6, lane = t & 63;
    const int c = lane & 15, g = lane >> 4;
    const int rk = t >> 3, ck = (t & 7) * 8;
    const int rv = t >> 2, cv = (t & 3) * 8;

    const int gid = blockIdx.x;
    const int bh = (gid & 7) + 8 * ((gid >> 3) & 3);
    const int xt = gid >> 5;
    const int b = bh >> 4, hh = bh & 15;
    const int qb = xt * 128 + w * 32;

    const ushort_t* Qh = Qr + (size_t)bh * (2048 * 64);
    const ushort_t* Kh = Kr + (size_t)bh * (2048 * 64);
    const ushort_t* Vh = Vt + (size_t)bh * (64 * 2048);
    const float*   crb = cr + (size_t)b * (2048 * 2);

    short8 bq[2][2];
#pragma unroll
    for (int qt = 0; qt < 2; ++qt)
#pragma unroll
        for (int st = 0; st < 2; ++st)
            bq[qt][st] = ld8(Qh + (size_t)(qb + qt * 16 + c) * 64 + st * 32 + 8 * g);

    f32x4 accv[2][4];
    const f32x4 zero4 = {0.f, 0.f, 0.f, 0.f};
#pragma unroll
    for (int qt = 0; qt < 2; ++qt)
#pragma unroll
        for (int dt = 0; dt < 4; ++dt) accv[qt][dt] = zero4;

    float lst[2] = {0.f, 0.f};
    float a0s[2] = {0.f, 0.f};
    float a1s[2] = {0.f, 0.f};

    float4 cA[2][2], cB[2][2];

    {
        const short8 k0 = ld8(Kh + (size_t)rk * 64 + ck);
        const short8 v0 = ld8(Vh + (size_t)rv * 2048 + cv);
        *reinterpret_cast<short8*>(&Ks[0][rk * 72 + ck]) = k0;
        *reinterpret_cast<short8*>(&Vs[0][rv * 40 + cv]) = v0;
        const float* cp0 = crb + (size_t)(4 * g) * 2;
        cA[0][0] = *reinterpret_cast<const float4*>(cp0);
        cA[0][1] = *reinterpret_cast<const float4*>(cp0 + 4);
        const float* cp1 = crb + (size_t)(16 + 4 * g) * 2;
        cA[1][0] = *reinterpret_cast<const float4*>(cp1);
        cA[1][1] = *reinterpret_cast<const float4*>(cp1 + 4);
    }
    __syncthreads();

    for (int i = 0; i < 32; ++i) {
        const int kvb = i * 64;
        attn_body(Kh, Vh, crb, kvb + 32,
                  &Ks[0][0], &Vs[0][0], &Ks[1][0], &Vs[1][0],
                  c, g, rk, ck, rv, cv, bq, cA, cB,
                  accv, lst, a0s, a1s);
        attn_body(Kh, Vh, crb, (kvb + 64) & 2047,
                  &Ks[1][0], &Vs[1][0], &Ks[0][0], &Vs[0][0],
                  c, g, rk, ck, rv, cv, bq, cB, cA,
                  accv, lst, a0s, a1s);
    }

#pragma unroll
    for (int qt = 0; qt < 2; ++qt) {
        lst[qt] += __shfl_xor(lst[qt], 16, 64); lst[qt] += __shfl_xor(lst[qt], 32, 64);
        a0s[qt] += __shfl_xor(a0s[qt], 16, 64); a0s[qt] += __shfl_xor(a0s[qt], 32, 64);
        a1s[qt] += __shfl_xor(a1s[qt], 16, 64); a1s[qt] += __shfl_xor(a1s[qt], 32, 64);
    }

#pragma unroll
    for (int qt = 0; qt < 2; ++qt) {
        const int q = qb + qt * 16 + c;
        const float inv = 1.f / lst[qt];
        const float a0 = a0s[qt] * inv, a1 = a1s[qt] * inv;
#pragma unroll
        for (int dt = 0; dt < 4; ++dt) {
            const int d = hh * 64 + dt * 16 + 4 * g;
            const float4 w0 = *reinterpret_cast<const float4*>(Wmo + d);
            const float4 w1 = *reinterpret_cast<const float4*>(Wmo + 1024 + d);
            const float4 bm = *reinterpret_cast<const float4*>(bmo + d);
            const size_t oidx = ((size_t)(b * 2048 + q)) * 1024 + d;
            float4 hv, mv;
            hv.x = accv[qt][dt][0] * inv; hv.y = accv[qt][dt][1] * inv;
            hv.z = accv[qt][dt][2] * inv; hv.w = accv[qt][dt][3] * inv;
            mv.x = a0 * w0.x + a1 * w1.x + bm.x;
            mv.y = a0 * w0.y + a1 * w1.y + bm.y;
            mv.z = a0 * w0.z + a1 * w1.z + bm.z;
            mv.w = a0 * w0.w + a1 * w1.w + bm.w;
            *reinterpret_cast<float4*>(out + oidx) = hv;
            *reinterpret_cast<float4*>(out + 4194304 + oidx) = mv;
        }
    }
}

// ---------------------------------------------------------------------------
extern "C" void kernel_launch(void* const* d_in, const int* in_sizes, int n_in,
                              void* d_out, int out_size, void* d_ws, size_t ws_size,
                              hipStream_t stream)
{
    const float* i1  = (const float*)d_in[0];
    const float* i2  = (const float*)d_in[1];
    const float* cr  = (const float*)d_in[2];
    const float* Wq  = (const float*)d_in[3];
    const float* bq  = (const float*)d_in[4];
    const float* Wkv = (const float*)d_in[5];
    const float* bkv = (const float*)d_in[6];
    const float* Wmo = (const float*)d_in[7];
    const float* bmo = (const float*)d_in[8];
    float* out = (float*)d_out;

    ushort_t* Qr = (ushort_t*)d_ws;          // [2,16,2048,64] bf16 (8 MB)
    ushort_t* Kr = Qr + 4194304;             // [2,16,2048,64] bf16 (8 MB)
    ushort_t* Vt = Kr + 4194304;             // [2,16,64,2048] bf16 (8 MB)

    // fast path needs 46 MB of ws: + A1(8) A2(8) Wqt(2) Wkvt(4)
    if (ws_size >= 48234496ULL) {
        ushort_t* A1   = Vt + 4194304;
        ushort_t* A2   = A1 + 4194304;
        ushort_t* Wqt  = A2 + 4194304;
        ushort_t* Wkvt = Wqt + 1048576;
        cvt_bf16<<<dim3(2048), dim3(256), 0, stream>>>(i1, A1);
        cvt_bf16<<<dim3(2048), dim3(256), 0, stream>>>(i2, A2);
        tcvt_bf16<<<dim3(16, 16), dim3(256), 0, stream>>>(Wq, Wqt, 1024, 1024);
        tcvt_bf16<<<dim3(32, 16), dim3(256), 0, stream>>>(Wkv, Wkvt, 1024, 2048);
        proj_all<<<dim3(24, 32), dim3(256), 0, stream>>>(A1, A2, Wqt, Wkvt, bq, bkv, Qr, Kr, Vt);
    } else {
        proj_gemm<<<dim3(8, 32), dim3(256), 0, stream>>>(i1, Wq, bq, 1024, Qr, nullptr);
        proj_gemm<<<dim3(16, 32), dim3(256), 0, stream>>>(i2, Wkv, bkv, 2048, Kr, Vt);
    }
    attn_kernel<<<dim3(512), dim3(256), 0, stream>>>(Qr, Kr, Vt, cr, Wmo, bmo, out);
}

// Round 10
// 132.355 us; speedup vs baseline: 3.0382x; 1.1173x over previous
//
#include <hip/hip_runtime.h>
#include <hip/hip_bf16.h>

typedef __attribute__((ext_vector_type(8))) short short8;
typedef __attribute__((ext_vector_type(4))) short short4_t;
typedef __attribute__((ext_vector_type(4))) float f32x4;
typedef unsigned short ushort_t;

#define DEV __device__ __forceinline__

DEV ushort_t f2bf(float f) {
    unsigned u = __builtin_bit_cast(unsigned, f);
    u = u + 0x7fffu + ((u >> 16) & 1u);   // RNE
    return (ushort_t)(u >> 16);
}

DEV unsigned pk_bf16(float lo, float hi) {
    __hip_bfloat162 h = __float22bfloat162_rn(make_float2(lo, hi));
    unsigned u;
    __builtin_memcpy(&u, &h, sizeof(u));
    return u;
}

// raw v_exp_f32: single TRANS-pipe instr; exact for |x| <= ~100 (our args <= ~10).
DEV float fast_exp2(float x) {
#if __has_builtin(__builtin_amdgcn_exp2f)
    return __builtin_amdgcn_exp2f(x);
#else
    float r;
    asm("v_exp_f32 %0, %1" : "=v"(r) : "v"(x));
    return r;
#endif
}

DEV short8 ld8(const ushort_t* p) { return *reinterpret_cast<const short8*>(p); }

// ---------------------------------------------------------------------------
// prep: f32 -> bf16 elementwise (grid*256*8 == n exactly)
// ---------------------------------------------------------------------------
__global__ __launch_bounds__(256)
void cvt_bf16(const float* __restrict__ in, ushort_t* __restrict__ out)
{
    const size_t i = ((size_t)blockIdx.x * 256 + threadIdx.x) * 8;
    const float4 a = *reinterpret_cast<const float4*>(in + i);
    const float4 b = *reinterpret_cast<const float4*>(in + i + 4);
    short8 v;
    v[0] = (short)f2bf(a.x); v[1] = (short)f2bf(a.y);
    v[2] = (short)f2bf(a.z); v[3] = (short)f2bf(a.w);
    v[4] = (short)f2bf(b.x); v[5] = (short)f2bf(b.y);
    v[6] = (short)f2bf(b.z); v[7] = (short)f2bf(b.w);
    *reinterpret_cast<short8*>(out + i) = v;
}

// ---------------------------------------------------------------------------
// prep: W[K][N] f32 -> Wt[N][K] bf16 (64x64 tiles via LDS)
// ---------------------------------------------------------------------------
__global__ __launch_bounds__(256)
void tcvt_bf16(const float* __restrict__ W, ushort_t* __restrict__ Wt, int K, int N)
{
    __shared__ ushort_t tile[64][72];
    const int t = threadIdx.x;
    const int nx = blockIdx.x * 64, ky = blockIdx.y * 64;
    const int r = t >> 2, q = (t & 3) * 16;

    const float* src = W + (size_t)(ky + r) * N + nx + q;
#pragma unroll
    for (int i = 0; i < 4; ++i) {
        const float4 v = *reinterpret_cast<const float4*>(src + 4 * i);
        tile[r][q + 4 * i + 0] = f2bf(v.x);
        tile[r][q + 4 * i + 1] = f2bf(v.y);
        tile[r][q + 4 * i + 2] = f2bf(v.z);
        tile[r][q + 4 * i + 3] = f2bf(v.w);
    }
    __syncthreads();
    short8 o0, o1;
#pragma unroll
    for (int i = 0; i < 8; ++i) {
        o0[i] = (short)tile[q + i][r];
        o1[i] = (short)tile[q + 8 + i][r];
    }
    ushort_t* dst = Wt + (size_t)(nx + r) * K + ky + q;
    *reinterpret_cast<short8*>(dst) = o0;
    *reinterpret_cast<short8*>(dst + 8) = o1;
}

// ---------------------------------------------------------------------------
// Fused projections (fast path): nblk<8 -> Q = A1 @ WqT; else KV = A2 @ WkvT.
// ---------------------------------------------------------------------------
__global__ __launch_bounds__(256, 2)
void proj_all(const ushort_t* __restrict__ A1, const ushort_t* __restrict__ A2,
              const ushort_t* __restrict__ Wqt, const ushort_t* __restrict__ Wkvt,
              const float* __restrict__ bqv, const float* __restrict__ bkv,
              ushort_t* __restrict__ Qr, ushort_t* __restrict__ Kr,
              ushort_t* __restrict__ Vt)
{
    __shared__ ushort_t As[128 * 72];
    __shared__ ushort_t Bs[128 * 72];

    const int t = threadIdx.x;
    const int lane = t & 63;
    const int wv = t >> 6;
    const int wr = wv >> 1, wc = wv & 1;
    const int c = lane & 15, g = lane >> 4;
    const int m0 = blockIdx.y * 128;
    const int nblk = blockIdx.x;

    const ushort_t* A;
    const ushort_t* Wt;
    const float* bias;
    int n0;
    if (nblk < 8) { A = A1; Wt = Wqt;  bias = bqv; n0 = nblk * 128; }
    else          { A = A2; Wt = Wkvt; bias = bkv; n0 = (nblk - 8) * 128; }
    const bool isQ = (nblk < 8);

    f32x4 acc[4][4];
    const f32x4 zero4 = {0.f, 0.f, 0.f, 0.f};
#pragma unroll
    for (int mi = 0; mi < 4; ++mi)
#pragma unroll
        for (int ni = 0; ni < 4; ++ni) acc[mi][ni] = zero4;

    const int srow[4] = { (t + 0)   >> 3, (t + 256) >> 3, (t + 512) >> 3, (t + 768) >> 3 };
    const int skq     = (t & 7) * 8;

    short8 a_reg[4], b_reg[4];
#pragma unroll
    for (int rep = 0; rep < 4; ++rep) {
        a_reg[rep] = ld8(A  + (size_t)(m0 + srow[rep]) * 1024 + skq);
        b_reg[rep] = ld8(Wt + (size_t)(n0 + srow[rep]) * 1024 + skq);
    }

    for (int it = 0; it < 16; ++it) {
#pragma unroll
        for (int rep = 0; rep < 4; ++rep) {
            *reinterpret_cast<short8*>(&As[srow[rep] * 72 + skq]) = a_reg[rep];
            *reinterpret_cast<short8*>(&Bs[srow[rep] * 72 + skq]) = b_reg[rep];
        }
        __syncthreads();
        if (it < 15) {
            const int k1 = (it + 1) * 64;
#pragma unroll
            for (int rep = 0; rep < 4; ++rep) {
                a_reg[rep] = ld8(A  + (size_t)(m0 + srow[rep]) * 1024 + k1 + skq);
                b_reg[rep] = ld8(Wt + (size_t)(n0 + srow[rep]) * 1024 + k1 + skq);
            }
        }
#pragma unroll
        for (int kk = 0; kk < 64; kk += 32) {
            short8 afr[4], bfr[4];
#pragma unroll
            for (int mi = 0; mi < 4; ++mi)
                afr[mi] = ld8(&As[(wr * 64 + mi * 16 + c) * 72 + kk + 8 * g]);
#pragma unroll
            for (int ni = 0; ni < 4; ++ni)
                bfr[ni] = ld8(&Bs[(wc * 64 + ni * 16 + c) * 72 + kk + 8 * g]);
#pragma unroll
            for (int mi = 0; mi < 4; ++mi)
#pragma unroll
                for (int ni = 0; ni < 4; ++ni)
                    acc[mi][ni] = __builtin_amdgcn_mfma_f32_16x16x32_bf16(
                        afr[mi], bfr[ni], acc[mi][ni], 0, 0, 0);
        }
        __syncthreads();
    }

#pragma unroll
    for (int mi = 0; mi < 4; ++mi) {
#pragma unroll
        for (int ni = 0; ni < 4; ++ni) {
            const int n = n0 + wc * 64 + ni * 16 + c;
            const float bb = bias[n];
#pragma unroll
            for (int j = 0; j < 4; ++j) {
                const int m = m0 + wr * 64 + mi * 16 + 4 * g + j;
                const int b = m >> 11, s = m & 2047;
                const ushort_t val = f2bf(acc[mi][ni][j] + bb);
                if (isQ) {
                    Qr[((size_t)((b * 16 + (n >> 6)) * 2048 + s)) * 64 + (n & 63)] = val;
                } else if (n < 1024) {
                    Kr[((size_t)((b * 16 + (n >> 6)) * 2048 + s)) * 64 + (n & 63)] = val;
                } else {
                    const int np = n - 1024;
                    Vt[(size_t)((b * 16 + (np >> 6)) * 64 + (np & 63)) * 2048 + s] = val;
                }
            }
        }
    }
}

// ---------------------------------------------------------------------------
// Fallback projection (r3/r8-proven): used if ws_size is too small for prep.
// ---------------------------------------------------------------------------
__global__ __launch_bounds__(256)
void proj_gemm(const float* __restrict__ A, const float* __restrict__ W,
               const float* __restrict__ bias, int N,
               ushort_t* __restrict__ outRow, ushort_t* __restrict__ outT)
{
    __shared__ ushort_t As[128 * 72];
    __shared__ ushort_t Bt[128 * 72];

    const int t = threadIdx.x;
    const int lane = t & 63;
    const int wv = t >> 6;
    const int wr = wv >> 1, wc = wv & 1;
    const int c = lane & 15, g = lane >> 4;
    const int m0 = blockIdx.y * 128, n0 = blockIdx.x * 128;

    f32x4 acc[4][4];
    const f32x4 zero4 = {0.f, 0.f, 0.f, 0.f};
#pragma unroll
    for (int mi = 0; mi < 4; ++mi)
#pragma unroll
        for (int ni = 0; ni < 4; ++ni) acc[mi][ni] = zero4;

    for (int it = 0; it < 16; ++it) {
        const int k0 = it * 64;
        {
            const int kq = (t & 15) * 4;
            int r = t >> 4;
#pragma unroll
            for (int rep = 0; rep < 8; ++rep, r += 16) {
                float4 v = *reinterpret_cast<const float4*>(
                    A + (size_t)(m0 + r) * 1024 + k0 + kq);
                ushort_t* dst = &As[r * 72 + kq];
                dst[0] = f2bf(v.x); dst[1] = f2bf(v.y);
                dst[2] = f2bf(v.z); dst[3] = f2bf(v.w);
            }
        }
        {
            const int nq = (t & 31) * 4;
            const int kr = t >> 5;
#pragma unroll
            for (int rep = 0; rep < 8; ++rep) {
                const int k = kr + 8 * rep;
                float4 v = *reinterpret_cast<const float4*>(
                    W + (size_t)(k0 + k) * N + n0 + nq);
                Bt[(nq + 0) * 72 + k] = f2bf(v.x);
                Bt[(nq + 1) * 72 + k] = f2bf(v.y);
                Bt[(nq + 2) * 72 + k] = f2bf(v.z);
                Bt[(nq + 3) * 72 + k] = f2bf(v.w);
            }
        }
        __syncthreads();
#pragma unroll
        for (int kk = 0; kk < 64; kk += 32) {
            short8 afr[4], bfr[4];
#pragma unroll
            for (int mi = 0; mi < 4; ++mi)
                afr[mi] = ld8(&As[(wr * 64 + mi * 16 + c) * 72 + kk + 8 * g]);
#pragma unroll
            for (int ni = 0; ni < 4; ++ni)
                bfr[ni] = ld8(&Bt[(wc * 64 + ni * 16 + c) * 72 + kk + 8 * g]);
#pragma unroll
            for (int mi = 0; mi < 4; ++mi)
#pragma unroll
                for (int ni = 0; ni < 4; ++ni)
                    acc[mi][ni] = __builtin_amdgcn_mfma_f32_16x16x32_bf16(
                        afr[mi], bfr[ni], acc[mi][ni], 0, 0, 0);
        }
        __syncthreads();
    }

#pragma unroll
    for (int mi = 0; mi < 4; ++mi) {
#pragma unroll
        for (int ni = 0; ni < 4; ++ni) {
            const int n = n0 + wc * 64 + ni * 16 + c;
            const float bb = bias[n];
#pragma unroll
            for (int j = 0; j < 4; ++j) {
                const int m = m0 + wr * 64 + mi * 16 + 4 * g + j;
                const int b = m >> 11, s = m & 2047;
                const ushort_t val = f2bf(acc[mi][ni][j] + bb);
                if (outT != nullptr && n >= 1024) {
                    const int np = n - 1024;
                    const int hh = np >> 6, d = np & 63;
                    outT[(size_t)((b * 16 + hh) * 64 + d) * 2048 + s] = val;
                } else {
                    const int hh = n >> 6, d = n & 63;
                    outRow[((size_t)((b * 16 + hh) * 2048 + s)) * 64 + d] = val;
                }
            }
        }
    }
}

// ---------------------------------------------------------------------------
// Flash attention (r8 structure): fixed-max softmax (raw v_exp_f32), PV^T,
// LDS double-buffered staging.
// ---------------------------------------------------------------------------
DEV void attn_body(const ushort_t* __restrict__ Kh, const ushort_t* __restrict__ Vh,
                   const float* __restrict__ crb, int kv_next,
                   const ushort_t* KsC, const ushort_t* VsC,
                   ushort_t* KsN, ushort_t* VsN,
                   int c, int g, int rk, int ck, int rv, int cv,
                   const short8 (&bq)[2][2],
                   float4 (&CC)[2][2], float4 (&CN)[2][2],
                   f32x4 (&accv)[2][4], float (&lst)[2],
                   float (&a0s)[2], float (&a1s)[2])
{
    const f32x4 zero4 = {0.f, 0.f, 0.f, 0.f};
    const float SCL = 0.18033688011112042f;  // (1/8) * log2(e)

    const short8 kreg = ld8(Kh + (size_t)(kv_next + rk) * 64 + ck);
    const short8 vreg = ld8(Vh + (size_t)rv * 2048 + kv_next + cv);
    {
        const float* cp0 = crb + (size_t)(kv_next + 4 * g) * 2;
        CN[0][0] = *reinterpret_cast<const float4*>(cp0);
        CN[0][1] = *reinterpret_cast<const float4*>(cp0 + 4);
        const float* cp1 = crb + (size_t)(kv_next + 16 + 4 * g) * 2;
        CN[1][0] = *reinterpret_cast<const float4*>(cp1);
        CN[1][1] = *reinterpret_cast<const float4*>(cp1 + 4);
    }
    __builtin_amdgcn_sched_barrier(0);

    short8 KC[2][2];
#pragma unroll
    for (int ct = 0; ct < 2; ++ct)
#pragma unroll
        for (int st = 0; st < 2; ++st)
            KC[ct][st] = ld8(&KsC[(ct * 16 + c) * 72 + st * 32 + 8 * g]);
    short8 VC[4];
#pragma unroll
    for (int dt = 0; dt < 4; ++dt) {
        const short4_t vlo = *reinterpret_cast<const short4_t*>(&VsC[(dt * 16 + c) * 40 + 4 * g]);
        const short4_t vhi = *reinterpret_cast<const short4_t*>(&VsC[(dt * 16 + c) * 40 + 4 * g + 16]);
        VC[dt] = __builtin_shufflevector(vlo, vhi, 0, 1, 2, 3, 4, 5, 6, 7);
    }

    f32x4 sc[2][2];
#pragma unroll
    for (int qt = 0; qt < 2; ++qt)
#pragma unroll
        for (int ct = 0; ct < 2; ++ct) {
            f32x4 z = zero4;
            z = __builtin_amdgcn_mfma_f32_16x16x32_bf16(KC[ct][0], bq[qt][0], z, 0, 0, 0);
            z = __builtin_amdgcn_mfma_f32_16x16x32_bf16(KC[ct][1], bq[qt][1], z, 0, 0, 0);
            sc[qt][ct] = z;
        }

    short8 pa[2];
#pragma unroll
    for (int qt = 0; qt < 2; ++qt) {
        float e[2][4];
        float lc = lst[qt], a0c = a0s[qt], a1c = a1s[qt];
#pragma unroll
        for (int ct = 0; ct < 2; ++ct) {
            const float cr0[4] = {CC[ct][0].x, CC[ct][0].z, CC[ct][1].x, CC[ct][1].z};
            const float cr1[4] = {CC[ct][0].y, CC[ct][0].w, CC[ct][1].y, CC[ct][1].w};
#pragma unroll
            for (int j = 0; j < 4; ++j) {
                const float ev = fast_exp2(sc[qt][ct][j] * SCL);
                e[ct][j] = ev;
                lc  += ev;
                a0c += ev * cr0[j];
                a1c += ev * cr1[j];
            }
        }
        lst[qt] = lc; a0s[qt] = a0c; a1s[qt] = a1c;
        int4 w;
        w.x = (int)pk_bf16(e[0][0], e[0][1]);
        w.y = (int)pk_bf16(e[0][2], e[0][3]);
        w.z = (int)pk_bf16(e[1][0], e[1][1]);
        w.w = (int)pk_bf16(e[1][2], e[1][3]);
        pa[qt] = __builtin_bit_cast(short8, w);
    }

#pragma unroll
    for (int dt = 0; dt < 4; ++dt) {
        accv[0][dt] = __builtin_amdgcn_mfma_f32_16x16x32_bf16(VC[dt], pa[0], accv[0][dt], 0, 0, 0);
        accv[1][dt] = __builtin_amdgcn_mfma_f32_16x16x32_bf16(VC[dt], pa[1], accv[1][dt], 0, 0, 0);
    }

    *reinterpret_cast<short8*>(&KsN[rk * 72 + ck]) = kreg;
    *reinterpret_cast<short8*>(&VsN[rv * 40 + cv]) = vreg;
    __syncthreads();
}

__global__ __launch_bounds__(256, 2)
void attn_kernel(const ushort_t* __restrict__ Qr, const ushort_t* __restrict__ Kr,
                 const ushort_t* __restrict__ Vt, const float* __restrict__ cr,
                 const float* __restrict__ Wmo, const float* __restrict__ bmo,
                 float* __restrict__ out)
{
    __shared__ ushort_t Ks[2][32 * 72];
    __shared__ ushort_t Vs[2][64 * 40];

    const int t = threadIdx.x;
    const int w = t >> 6, lane = t & 63;
    const int c = lane & 15, g = lane >> 4;
    const int rk = t >> 3, ck = (t & 7) * 8;
    const int rv = t >> 2, cv = (t & 3) * 8;

    const int gid = blockIdx.x;
    const int bh = (gid & 7) + 8 * ((gid >> 3) & 3);
    const int xt = gid >> 5;
    const int b = bh >> 4, hh = bh & 15;
    const int qb = xt * 128 + w * 32;

    const ushort_t* Qh = Qr + (size_t)bh * (2048 * 64);
    const ushort_t* Kh = Kr + (size_t)bh * (2048 * 64);
    const ushort_t* Vh = Vt + (size_t)bh * (64 * 2048);
    const float*   crb = cr + (size_t)b * (2048 * 2);

    short8 bq[2][2];
#pragma unroll
    for (int qt = 0; qt < 2; ++qt)
#pragma unroll
        for (int st = 0; st < 2; ++st)
            bq[qt][st] = ld8(Qh + (size_t)(qb + qt * 16 + c) * 64 + st * 32 + 8 * g);

    f32x4 accv[2][4];
    const f32x4 zero4 = {0.f, 0.f, 0.f, 0.f};
#pragma unroll
    for (int qt = 0; qt < 2; ++qt)
#pragma unroll
        for (int dt = 0; dt < 4; ++dt) accv[qt][dt] = zero4;

    float lst[2] = {0.f, 0.f};
    float a0s[2] = {0.f, 0.f};
    float a1s[2] = {0.f, 0.f};

    float4 cA[2][2], cB[2][2];

    {
        const short8 k0 = ld8(Kh + (size_t)rk * 64 + ck);
        const short8 v0 = ld8(Vh + (size_t)rv * 2048 + cv);
        *reinterpret_cast<short8*>(&Ks[0][rk * 72 + ck]) = k0;
        *reinterpret_cast<short8*>(&Vs[0][rv * 40 + cv]) = v0;
        const float* cp0 = crb + (size_t)(4 * g) * 2;
        cA[0][0] = *reinterpret_cast<const float4*>(cp0);
        cA[0][1] = *reinterpret_cast<const float4*>(cp0 + 4);
        const float* cp1 = crb + (size_t)(16 + 4 * g) * 2;
        cA[1][0] = *reinterpret_cast<const float4*>(cp1);
        cA[1][1] = *reinterpret_cast<const float4*>(cp1 + 4);
    }
    __syncthreads();

    for (int i = 0; i < 32; ++i) {
        const int kvb = i * 64;
        attn_body(Kh, Vh, crb, kvb + 32,
                  &Ks[0][0], &Vs[0][0], &Ks[1][0], &Vs[1][0],
                  c, g, rk, ck, rv, cv, bq, cA, cB,
                  accv, lst, a0s, a1s);
        attn_body(Kh, Vh, crb, (kvb + 64) & 2047,
                  &Ks[1][0], &Vs[1][0], &Ks[0][0], &Vs[0][0],
                  c, g, rk, ck, rv, cv, bq, cB, cA,
                  accv, lst, a0s, a1s);
    }

#pragma unroll
    for (int qt = 0; qt < 2; ++qt) {
        lst[qt] += __shfl_xor(lst[qt], 16, 64); lst[qt] += __shfl_xor(lst[qt], 32, 64);
        a0s[qt] += __shfl_xor(a0s[qt], 16, 64); a0s[qt] += __shfl_xor(a0s[qt], 32, 64);
        a1s[qt] += __shfl_xor(a1s[qt], 16, 64); a1s[qt] += __shfl_xor(a1s[qt], 32, 64);
    }

#pragma unroll
    for (int qt = 0; qt < 2; ++qt) {
        const int q = qb + qt * 16 + c;
        const float inv = 1.f / lst[qt];
        const float a0 = a0s[qt] * inv, a1 = a1s[qt] * inv;
#pragma unroll
        for (int dt = 0; dt < 4; ++dt) {
            const int d = hh * 64 + dt * 16 + 4 * g;
            const float4 w0 = *reinterpret_cast<const float4*>(Wmo + d);
            const float4 w1 = *reinterpret_cast<const float4*>(Wmo + 1024 + d);
            const float4 bm = *reinterpret_cast<const float4*>(bmo + d);
            const size_t oidx = ((size_t)(b * 2048 + q)) * 1024 + d;
            float4 hv, mv;
            hv.x = accv[qt][dt][0] * inv; hv.y = accv[qt][dt][1] * inv;
            hv.z = accv[qt][dt][2] * inv; hv.w = accv[qt][dt][3] * inv;
            mv.x = a0 * w0.x + a1 * w1.x + bm.x;
            mv.y = a0 * w0.y + a1 * w1.y + bm.y;
            mv.z = a0 * w0.z + a1 * w1.z + bm.z;
            mv.w = a0 * w0.w + a1 * w1.w + bm.w;
            *reinterpret_cast<float4*>(out + oidx) = hv;
            *reinterpret_cast<float4*>(out + 4194304 + oidx) = mv;
        }
    }
}

// ---------------------------------------------------------------------------
extern "C" void kernel_launch(void* const* d_in, const int* in_sizes, int n_in,
                              void* d_out, int out_size, void* d_ws, size_t ws_size,
                              hipStream_t stream)
{
    const float* i1  = (const float*)d_in[0];
    const float* i2  = (const float*)d_in[1];
    const float* cr  = (const float*)d_in[2];
    const float* Wq  = (const float*)d_in[3];
    const float* bq  = (const float*)d_in[4];
    const float* Wkv = (const float*)d_in[5];
    const float* bkv = (const float*)d_in[6];
    const float* Wmo = (const float*)d_in[7];
    const float* bmo = (const float*)d_in[8];
    float* out = (float*)d_out;

    ushort_t* Qr = (ushort_t*)d_ws;          // [2,16,2048,64] bf16 (8 MB)
    ushort_t* Kr = Qr + 4194304;             // [2,16,2048,64] bf16 (8 MB)
    ushort_t* Vt = Kr + 4194304;             // [2,16,64,2048] bf16 (8 MB)

    // fast path needs 46 MB of ws: + A1(8) A2(8) Wqt(2) Wkvt(4)
    if (ws_size >= 48234496ULL) {
        ushort_t* A1   = Vt + 4194304;
        ushort_t* A2   = A1 + 4194304;
        ushort_t* Wqt  = A2 + 4194304;
        ushort_t* Wkvt = Wqt + 1048576;
        cvt_bf16<<<dim3(2048), dim3(256), 0, stream>>>(i1, A1);
        cvt_bf16<<<dim3(2048), dim3(256), 0, stream>>>(i2, A2);
        tcvt_bf16<<<dim3(16, 16), dim3(256), 0, stream>>>(Wq, Wqt, 1024, 1024);
        tcvt_bf16<<<dim3(32, 16), dim3(256), 0, stream>>>(Wkv, Wkvt, 1024, 2048);
        proj_all<<<dim3(24, 32), dim3(256), 0, stream>>>(A1, A2, Wqt, Wkvt, bq, bkv, Qr, Kr, Vt);
    } else {
        proj_gemm<<<dim3(8, 32), dim3(256), 0, stream>>>(i1, Wq, bq, 1024, Qr, nullptr);
        proj_gemm<<<dim3(16, 32), dim3(256), 0, stream>>>(i2, Wkv, bkv, 2048, Kr, Vt);
    }
    attn_kernel<<<dim3(512), dim3(256), 0, stream>>>(Qr, Kr, Vt, cr, Wmo, bmo, out);
}